// Round 17
// baseline (125.664 us; speedup 1.0000x reference)
//
#include <hip/hip_runtime.h>
#include <hip/hip_bf16.h>

// TokenEncoder: B=8 L=2048 D=512 DM=1024 S=32 M=4 P=4096
// out = [tokens (8,2049,1024) f32][attn_keep (8,2049) as f32]

#define NB   8
#define NL   2048
#define ND   512
#define NDM  1024
#define NS   32
#define NTOK (NB * NL)          // 16384
#define LP1  (NL + 1)           // 2049
#define MAXTILES 160
#define EXP_CAP 1024

static __device__ __forceinline__ size_t attn_off() { return (size_t)NB * LP1 * NDM; }

typedef __attribute__((ext_vector_type(8))) short bf16x8;
typedef __attribute__((ext_vector_type(4))) float f32x4;

__device__ __forceinline__ unsigned short f2bf(float f) {
    unsigned int x = __float_as_uint(f);
    x += 0x7fffu + ((x >> 16) & 1u);   // RNE (inputs finite)
    return (unsigned short)(x >> 16);
}

__device__ __forceinline__ float bf2f(unsigned short s) {
    return __uint_as_float(((unsigned int)s) << 16);
}

// native conversion path: compiler emits v_cvt_pk_bf16_f32 (RNE)
__device__ __forceinline__ bf16x8 cvt8(float4 a, float4 b) {
    bf16x8 r;
    r[0] = (short)__bfloat16_as_ushort(__float2bfloat16(a.x));
    r[1] = (short)__bfloat16_as_ushort(__float2bfloat16(a.y));
    r[2] = (short)__bfloat16_as_ushort(__float2bfloat16(a.z));
    r[3] = (short)__bfloat16_as_ushort(__float2bfloat16(a.w));
    r[4] = (short)__bfloat16_as_ushort(__float2bfloat16(b.x));
    r[5] = (short)__bfloat16_as_ushort(__float2bfloat16(b.y));
    r[6] = (short)__bfloat16_as_ushort(__float2bfloat16(b.z));
    r[7] = (short)__bfloat16_as_ushort(__float2bfloat16(b.w));
    return r;
}

__device__ __forceinline__ float4 ld4(const float* p) { return *(const float4*)p; }
__device__ __forceinline__ float4 add4(float4 a, float4 b) {
    return make_float4(a.x + b.x, a.y + b.y, a.z + b.z, a.w + b.w);
}

// ---- kernel 1: bucket tokens per expert; kidx; attn mask; mrT table ----
__global__ void k_bucket(const int* __restrict__ sid, const int* __restrict__ mask,
                         const int* __restrict__ mod, const int* __restrict__ role,
                         const float* __restrict__ me, const float* __restrict__ re,
                         int* __restrict__ cnt, int* __restrict__ kidx,
                         int* __restrict__ tokList, float* __restrict__ mrT,
                         float* __restrict__ out) {
    int t = blockIdx.x * 256 + threadIdx.x;
    if (t < NTOK) {
        int s = sid[t];
        bool keep = mask[t] != 0;
        int b = t >> 11, l = t & (NL - 1);
        out[attn_off() + (size_t)b * LP1 + l + 1] = keep ? 1.0f : 0.0f;
        if (t < NB) out[attn_off() + (size_t)t * LP1] = 1.0f;   // CLS keep
        int ki = -1;
        if (keep) {
            ki = atomicAdd(&cnt[s], 1);
            if (ki < EXP_CAP) tokList[s * EXP_CAP + ki] = t;
        }
        kidx[t] = ki;
    }
    if (blockIdx.x < 12) {              // mod*role table (independent work)
        int mr = blockIdx.x, m = mr / 3, ro = mr % 3;
        int o = threadIdx.x * 4;        // 256*4 = 1024
        float4 v = add4(ld4(me + (size_t)m * NDM + o), ld4(re + (size_t)ro * NDM + o));
        *(float4*)&mrT[(size_t)mr * NDM + o] = v;
    }
}

// ---- kernel 2: grouped GEMM (r15 K-loop) + wave-local transposed epilogue ----
__global__ __launch_bounds__(256) void k_gemm(
    const float* __restrict__ emb, const float* __restrict__ Wp,
    const int* __restrict__ tokList, const int* __restrict__ cnt,
    unsigned short* __restrict__ projC) {
    // per-block tile walk: blockIdx.y -> (e, rowBase, nRows, cBase)
    int e = -1, rowBase = 0, nRows = 0, cBase = 0;
    {
        int T = blockIdx.y, idx = 0, cb = 0;
        for (int s = 0; s < NS; ++s) {
            int c = min(cnt[s], EXP_CAP);
            int nt = (c + 127) >> 7;
            if (T >= idx && T < idx + nt) {
                e = s; rowBase = (T - idx) * 128;
                nRows = min(128, c - rowBase); cBase = cb + rowBase;
            }
            idx += nt; cb += c;
        }
        if (e < 0) return;
    }
    const int nBase = blockIdx.x * 128;

    // unified LDS: K-loop uses [0,32KB) as SA[2]|SB[2]; epilogue reuses [0,17KB)
    __shared__ short LB[16384];             // 32 KB
    short* SAb = LB;                        // SA[buf] = LB + buf*4096
    short* SBb = LB + 8192;                 // SB[buf] = LB + 8192 + buf*4096

    const int tid  = threadIdx.x;
    const int lane = tid & 63;
    const int w    = tid >> 6;
    const int wr   = w >> 1, wc = w & 1;    // 2x2 waves, 64x64 out each
    const int fr   = lane & 15, kg = lane >> 4;

    // staging: thread covers rows (srow, srow+64), 8-elem chunk sch; ds_write
    // carries XOR swizzle chunk^((row>>1)&3); ds_read same involution (r8-proven).
    const int srow = tid >> 2;              // 0..63
    const int sch  = tid & 3;
    const size_t eBase = (size_t)e * EXP_CAP + rowBase;
    int ar0 = (srow < nRows) ? srow : 0;
    int ar1 = (srow + 64 < nRows) ? srow + 64 : 0;
    int tok0 = tokList[eBase + ar0];
    int tok1 = tokList[eBase + ar1];
    const float* a0 = emb + (size_t)tok0 * ND + sch * 8;
    const float* a1 = emb + (size_t)tok1 * ND + sch * 8;
    const float* b0 = Wp + ((size_t)e * NDM + nBase + srow) * ND + sch * 8;
    const float* b1 = Wp + ((size_t)e * NDM + nBase + srow + 64) * ND + sch * 8;
    const int wo0 = srow * 32 + (sch ^ ((srow >> 1) & 3)) * 8;
    const int wo1 = wo0 + 64 * 32;

    f32x4 acc[4][4];
#pragma unroll
    for (int i = 0; i < 4; ++i)
#pragma unroll
        for (int j = 0; j < 4; ++j)
            acc[i][j] = (f32x4){0.f, 0.f, 0.f, 0.f};

    float4 ta0a, ta0b, ta1a, ta1b, tb0a, tb0b, tb1a, tb1b;   // f32 tmp set (step+2)
    bf16x8 na0, na1, nb0, nb1;                                // bf16 set (next step)

#define LDF(ks) do {                                           \
        ta0a = ld4(a0 + (ks) * 32); ta0b = ld4(a0 + (ks) * 32 + 4); \
        ta1a = ld4(a1 + (ks) * 32); ta1b = ld4(a1 + (ks) * 32 + 4); \
        tb0a = ld4(b0 + (ks) * 32); tb0b = ld4(b0 + (ks) * 32 + 4); \
        tb1a = ld4(b1 + (ks) * 32); tb1b = ld4(b1 + (ks) * 32 + 4); \
    } while (0)
#define CVT() do {                                             \
        na0 = cvt8(ta0a, ta0b); na1 = cvt8(ta1a, ta1b);        \
        nb0 = cvt8(tb0a, tb0b); nb1 = cvt8(tb1a, tb1b);        \
    } while (0)

    // prologue: buf0 <- step0; bf set <- step1
    LDF(0); CVT();
    *(bf16x8*)&SAb[wo0] = na0;
    *(bf16x8*)&SAb[wo1] = na1;
    *(bf16x8*)&SBb[wo0] = nb0;
    *(bf16x8*)&SBb[wo1] = nb1;
    LDF(1); CVT();

    const int pc = kg ^ ((fr >> 1) & 3);    // swizzled physical chunk (lane-const)
    for (int ks = 0; ks < ND / 32; ++ks) {  // 16 K-steps
        const int cur = ks & 1;
        __syncthreads();                    // buf[cur] complete; buf[cur^1] free
        if (ks < ND / 32 - 1) {             // stage step ks+1 into the other buffer
            short* sa = SAb + (cur ^ 1) * 4096;
            short* sb = SBb + (cur ^ 1) * 4096;
            *(bf16x8*)&sa[wo0] = na0;
            *(bf16x8*)&sa[wo1] = na1;
            *(bf16x8*)&sb[wo0] = nb0;
            *(bf16x8*)&sb[wo1] = nb1;
        }
        if (ks < ND / 32 - 2) LDF(ks + 2);  // issue loads; retire under MFMA
        const short* sa = SAb + cur * 4096;
        const short* sb = SBb + cur * 4096;
        bf16x8 af[4], bv[4];
#pragma unroll
        for (int i = 0; i < 4; ++i)
            af[i] = *(const bf16x8*)&sa[(wr * 64 + i * 16 + fr) * 32 + pc * 8];
#pragma unroll
        for (int j = 0; j < 4; ++j)
            bv[j] = *(const bf16x8*)&sb[(wc * 64 + j * 16 + fr) * 32 + pc * 8];
#pragma unroll
        for (int i = 0; i < 4; ++i)
#pragma unroll
            for (int j = 0; j < 4; ++j)
                acc[i][j] = __builtin_amdgcn_mfma_f32_16x16x32_bf16(af[i], bv[j], acc[i][j], 0, 0, 0);
        if (ks < ND / 32 - 2) CVT();        // convert after MFMA (load slack ~1 phase)
    }
#undef LDF
#undef CVT

    // ---- epilogue: wave-local LDS transpose -> full-line 16B/lane projC writes
    __syncthreads();                        // K-loop LDS reads done in all waves
    short* EPW = LB + w * 2176;             // 32 rows x 68 shorts per wave (4.25KB)
#pragma unroll
    for (int h = 0; h < 2; ++h) {
        // write half-tile (acc i = h*2, h*2+1): rows 0..31 of this half
#pragma unroll
        for (int ii = 0; ii < 2; ++ii)
#pragma unroll
            for (int j = 0; j < 4; ++j)
#pragma unroll
                for (int r = 0; r < 4; ++r)
                    EPW[(ii * 16 + kg * 4 + r) * 68 + j * 16 + fr] =
                        (short)f2bf(acc[h * 2 + ii][j][r]);
        // read back row-major: 8 lanes per 64-col row-segment, 16B each
#pragma unroll
        for (int ps = 0; ps < 4; ++ps) {
            int lr   = ps * 8 + (lane >> 3);            // 0..31
            int grow = wr * 64 + h * 32 + lr;           // tile row
            bf16x8 v = *(const bf16x8*)&EPW[lr * 68 + (lane & 7) * 8];
            if (grow < nRows) {
                size_t dst = (size_t)(cBase + grow) * NDM + nBase + wc * 64 + (lane & 7) * 8;
                *(bf16x8*)&projC[dst] = v;
            }
        }
    }
}

// ---- kernel 3: ALL output rows; 2 rows/block, 8 floats/thread ----
__global__ void k_out(const int* __restrict__ pos, const int* __restrict__ sid,
                      const int* __restrict__ mod, const int* __restrict__ role,
                      const int* __restrict__ mask, const int* __restrict__ kidx,
                      const int* __restrict__ cnt,
                      const float* __restrict__ bp, const float* __restrict__ cls_c,
                      const float* __restrict__ pe, const float* __restrict__ ie,
                      const float* __restrict__ mrT,
                      const unsigned short* __restrict__ projC,
                      float* __restrict__ out) {
    __shared__ int scnt[NS];
    if (threadIdx.x < NS) scnt[threadIdx.x] = min(cnt[threadIdx.x], EXP_CAP);
    __syncthreads();
    int rp = threadIdx.x >> 7;          // row of pair
    int o  = (threadIdx.x & 127) * 8;   // 128 threads x 8 floats = 1024
    int l1 = blockIdx.x * 2 + rp;       // 0..2049
    int b  = blockIdx.y;
    if (l1 > NL) return;
    float4 v0, v1;
    if (l1 == 0) {
        const float* ieC = ie + (size_t)NS * NDM;
        v0 = add4(add4(ld4(cls_c + o), ld4(pe + o)), ld4(ieC + o));
        v1 = add4(add4(ld4(cls_c + o + 4), ld4(pe + o + 4)), ld4(ieC + o + 4));
    } else {
        int t = b * NL + l1 - 1;
        int p = pos[t], s = sid[t], mr = mod[t] * 3 + role[t];
        const float* peR = pe + (size_t)p * NDM + o;
        const float* ieR = ie + (size_t)s * NDM + o;
        const float* mrR = mrT + (size_t)mr * NDM + o;
        v0 = add4(add4(ld4(peR), ld4(ieR)), ld4(mrR));
        v1 = add4(add4(ld4(peR + 4), ld4(ieR + 4)), ld4(mrR + 4));
        if (mask[t] != 0) {
            const float* bpR = bp + (size_t)s * NDM + o;
            v0 = add4(v0, ld4(bpR));
            v1 = add4(v1, ld4(bpR + 4));
            int ki = kidx[t];
            if (ki >= 0 && ki < EXP_CAP) {
                int boff = 0;
                for (int q = 0; q < s; ++q) boff += scnt[q];
                const unsigned short* pr = projC + (size_t)(boff + ki) * NDM + o;
                v0.x += bf2f(pr[0]); v0.y += bf2f(pr[1]);
                v0.z += bf2f(pr[2]); v0.w += bf2f(pr[3]);
                v1.x += bf2f(pr[4]); v1.y += bf2f(pr[5]);
                v1.z += bf2f(pr[6]); v1.w += bf2f(pr[7]);
            }
        }
    }
    float* dst = &out[((size_t)b * LP1 + l1) * NDM + o];
    *(float4*)dst = v0;
    *(float4*)(dst + 4) = v1;
}

extern "C" void kernel_launch(void* const* d_in, const int* in_sizes, int n_in,
                              void* d_out, int out_size, void* d_ws, size_t ws_size,
                              hipStream_t stream) {
    const float* emb  = (const float*)d_in[0];
    const int* pos    = (const int*)d_in[1];
    const int* sid    = (const int*)d_in[2];
    const int* mod    = (const int*)d_in[3];
    const int* role   = (const int*)d_in[4];
    const int* mask   = (const int*)d_in[5];   // np.bool_ pushed as int32
    const float* Wp   = (const float*)d_in[6];
    const float* bp   = (const float*)d_in[7];
    const float* cls  = (const float*)d_in[8];
    const float* pe   = (const float*)d_in[9];
    const float* ie   = (const float*)d_in[10];
    const float* me   = (const float*)d_in[11];
    const float* re   = (const float*)d_in[12];
    float* out = (float*)d_out;

    int* ws        = (int*)d_ws;
    int* cnt       = ws;                          // [0..31]
    int* tokList   = ws + 1024;                   // 32*1024
    int* kidx      = ws + 33792;                  // 16384
    float* mrT     = (float*)(ws + 50176);        // 12*1024
    unsigned short* projC = (unsigned short*)((char*)d_ws + 262144);  // 33.55 MB
    // total ws: ~33.8 MB

    hipMemsetAsync(cnt, 0, 32 * sizeof(int), stream);
    k_bucket<<<NTOK / 256, 256, 0, stream>>>(sid, mask, mod, role, me, re,
                                             cnt, kidx, tokList, mrT, out);

    dim3 gg(NDM / 128, MAXTILES);   // N-slice fast -> A-tile L3 reuse
    k_gemm<<<gg, 256, 0, stream>>>(emb, Wp, tokList, cnt, projC);

    dim3 go((LP1 + 1) / 2, NB);
    k_out<<<go, 256, 0, stream>>>(pos, sid, mod, role, mask, kidx, cnt,
                                  bp, cls, pe, ie, mrT, projC, out);
}

// Round 18
// 122.382 us; speedup vs baseline: 1.0268x; 1.0268x over previous
//
#include <hip/hip_runtime.h>
#include <hip/hip_bf16.h>

// TokenEncoder: B=8 L=2048 D=512 DM=1024 S=32 M=4 P=4096
// out = [tokens (8,2049,1024) f32][attn_keep (8,2049) as f32]

#define NB   8
#define NL   2048
#define ND   512
#define NDM  1024
#define NS   32
#define NTOK (NB * NL)          // 16384
#define LP1  (NL + 1)           // 2049
#define MAXTILES 160
#define EXP_CAP 1024

static __device__ __forceinline__ size_t attn_off() { return (size_t)NB * LP1 * NDM; }

typedef __attribute__((ext_vector_type(8))) short bf16x8;
typedef __attribute__((ext_vector_type(4))) float f32x4;

__device__ __forceinline__ unsigned short f2bf(float f) {
    unsigned int x = __float_as_uint(f);
    x += 0x7fffu + ((x >> 16) & 1u);   // RNE (inputs finite)
    return (unsigned short)(x >> 16);
}

__device__ __forceinline__ float bf2f(unsigned short s) {
    return __uint_as_float(((unsigned int)s) << 16);
}

// native conversion path: compiler emits v_cvt_pk_bf16_f32 (RNE)
__device__ __forceinline__ bf16x8 cvt8(float4 a, float4 b) {
    bf16x8 r;
    r[0] = (short)__bfloat16_as_ushort(__float2bfloat16(a.x));
    r[1] = (short)__bfloat16_as_ushort(__float2bfloat16(a.y));
    r[2] = (short)__bfloat16_as_ushort(__float2bfloat16(a.z));
    r[3] = (short)__bfloat16_as_ushort(__float2bfloat16(a.w));
    r[4] = (short)__bfloat16_as_ushort(__float2bfloat16(b.x));
    r[5] = (short)__bfloat16_as_ushort(__float2bfloat16(b.y));
    r[6] = (short)__bfloat16_as_ushort(__float2bfloat16(b.z));
    r[7] = (short)__bfloat16_as_ushort(__float2bfloat16(b.w));
    return r;
}

__device__ __forceinline__ float4 ld4(const float* p) { return *(const float4*)p; }
__device__ __forceinline__ float4 add4(float4 a, float4 b) {
    return make_float4(a.x + b.x, a.y + b.y, a.z + b.z, a.w + b.w);
}

// ---- kernel 1: bucket tokens per expert; kidx; attn mask; mrT table ----
__global__ void k_bucket(const int* __restrict__ sid, const int* __restrict__ mask,
                         const int* __restrict__ mod, const int* __restrict__ role,
                         const float* __restrict__ me, const float* __restrict__ re,
                         int* __restrict__ cnt, int* __restrict__ kidx,
                         int* __restrict__ tokList, float* __restrict__ mrT,
                         float* __restrict__ out) {
    int t = blockIdx.x * 256 + threadIdx.x;
    if (t < NTOK) {
        int s = sid[t];
        bool keep = mask[t] != 0;
        int b = t >> 11, l = t & (NL - 1);
        out[attn_off() + (size_t)b * LP1 + l + 1] = keep ? 1.0f : 0.0f;
        if (t < NB) out[attn_off() + (size_t)t * LP1] = 1.0f;   // CLS keep
        int ki = -1;
        if (keep) {
            ki = atomicAdd(&cnt[s], 1);
            if (ki < EXP_CAP) tokList[s * EXP_CAP + ki] = t;
        }
        kidx[t] = ki;
    }
    if (blockIdx.x < 12) {              // mod*role table (independent work)
        int mr = blockIdx.x, m = mr / 3, ro = mr % 3;
        int o = threadIdx.x * 4;        // 256*4 = 1024
        float4 v = add4(ld4(me + (size_t)m * NDM + o), ld4(re + (size_t)ro * NDM + o));
        *(float4*)&mrT[(size_t)mr * NDM + o] = v;
    }
}

// ---- kernel 2: grouped GEMM (r15-proven): 128x128, BK=32, dbuf, fused cvt ----
__global__ __launch_bounds__(256) void k_gemm(
    const float* __restrict__ emb, const float* __restrict__ Wp,
    const int* __restrict__ tokList, const int* __restrict__ cnt,
    unsigned short* __restrict__ projC) {
    // per-block tile walk: blockIdx.y -> (e, rowBase, nRows, cBase)
    int e = -1, rowBase = 0, nRows = 0, cBase = 0;
    {
        int T = blockIdx.y, idx = 0, cb = 0;
        for (int s = 0; s < NS; ++s) {
            int c = min(cnt[s], EXP_CAP);
            int nt = (c + 127) >> 7;
            if (T >= idx && T < idx + nt) {
                e = s; rowBase = (T - idx) * 128;
                nRows = min(128, c - rowBase); cBase = cb + rowBase;
            }
            idx += nt; cb += c;
        }
        if (e < 0) return;
    }
    const int nBase = blockIdx.x * 128;

    __shared__ short SA[2][128 * 32];   // 8 KB per buffer
    __shared__ short SB[2][128 * 32];

    const int tid  = threadIdx.x;
    const int lane = tid & 63;
    const int w    = tid >> 6;
    const int wr   = w >> 1, wc = w & 1;    // 2x2 waves, 64x64 out each
    const int fr   = lane & 15, kg = lane >> 4;

    // staging: thread covers rows (srow, srow+64), 8-elem chunk sch; ds_write
    // carries XOR swizzle chunk^((row>>1)&3); ds_read same involution (r8-proven).
    const int srow = tid >> 2;              // 0..63
    const int sch  = tid & 3;
    const size_t eBase = (size_t)e * EXP_CAP + rowBase;
    int ar0 = (srow < nRows) ? srow : 0;
    int ar1 = (srow + 64 < nRows) ? srow + 64 : 0;
    int tok0 = tokList[eBase + ar0];
    int tok1 = tokList[eBase + ar1];
    const float* a0 = emb + (size_t)tok0 * ND + sch * 8;
    const float* a1 = emb + (size_t)tok1 * ND + sch * 8;
    const float* b0 = Wp + ((size_t)e * NDM + nBase + srow) * ND + sch * 8;
    const float* b1 = Wp + ((size_t)e * NDM + nBase + srow + 64) * ND + sch * 8;
    const int wo0 = srow * 32 + (sch ^ ((srow >> 1) & 3)) * 8;
    const int wo1 = wo0 + 64 * 32;

    f32x4 acc[4][4];
#pragma unroll
    for (int i = 0; i < 4; ++i)
#pragma unroll
        for (int j = 0; j < 4; ++j)
            acc[i][j] = (f32x4){0.f, 0.f, 0.f, 0.f};

    float4 ta0a, ta0b, ta1a, ta1b, tb0a, tb0b, tb1a, tb1b;   // f32 tmp set (step+2)
    bf16x8 na0, na1, nb0, nb1;                                // bf16 set (next step)

#define LDF(ks) do {                                           \
        ta0a = ld4(a0 + (ks) * 32); ta0b = ld4(a0 + (ks) * 32 + 4); \
        ta1a = ld4(a1 + (ks) * 32); ta1b = ld4(a1 + (ks) * 32 + 4); \
        tb0a = ld4(b0 + (ks) * 32); tb0b = ld4(b0 + (ks) * 32 + 4); \
        tb1a = ld4(b1 + (ks) * 32); tb1b = ld4(b1 + (ks) * 32 + 4); \
    } while (0)
#define CVT() do {                                             \
        na0 = cvt8(ta0a, ta0b); na1 = cvt8(ta1a, ta1b);        \
        nb0 = cvt8(tb0a, tb0b); nb1 = cvt8(tb1a, tb1b);        \
    } while (0)

    // prologue: buf0 <- step0; bf set <- step1
    LDF(0); CVT();
    *(bf16x8*)&SA[0][wo0] = na0;
    *(bf16x8*)&SA[0][wo1] = na1;
    *(bf16x8*)&SB[0][wo0] = nb0;
    *(bf16x8*)&SB[0][wo1] = nb1;
    LDF(1); CVT();

    const int pc = kg ^ ((fr >> 1) & 3);    // swizzled physical chunk (lane-const)
    for (int ks = 0; ks < ND / 32; ++ks) {  // 16 K-steps
        const int cur = ks & 1;
        __syncthreads();                    // buf[cur] complete; buf[cur^1] free
        if (ks < ND / 32 - 1) {             // stage step ks+1 into the other buffer
            *(bf16x8*)&SA[cur ^ 1][wo0] = na0;
            *(bf16x8*)&SA[cur ^ 1][wo1] = na1;
            *(bf16x8*)&SB[cur ^ 1][wo0] = nb0;
            *(bf16x8*)&SB[cur ^ 1][wo1] = nb1;
        }
        if (ks < ND / 32 - 2) LDF(ks + 2);  // issue loads; retire under MFMA
        bf16x8 af[4], bv[4];
#pragma unroll
        for (int i = 0; i < 4; ++i)
            af[i] = *(const bf16x8*)&SA[cur][(wr * 64 + i * 16 + fr) * 32 + pc * 8];
#pragma unroll
        for (int j = 0; j < 4; ++j)
            bv[j] = *(const bf16x8*)&SB[cur][(wc * 64 + j * 16 + fr) * 32 + pc * 8];
#pragma unroll
        for (int i = 0; i < 4; ++i)
#pragma unroll
            for (int j = 0; j < 4; ++j)
                acc[i][j] = __builtin_amdgcn_mfma_f32_16x16x32_bf16(af[i], bv[j], acc[i][j], 0, 0, 0);
        if (ks < ND / 32 - 2) CVT();        // convert after MFMA (load slack ~1 phase)
    }
#undef LDF
#undef CVT

    // epilogue: compact bf16 write, page-local (128 rows x 256KB window)
#pragma unroll
    for (int i = 0; i < 4; ++i) {
#pragma unroll
        for (int r = 0; r < 4; ++r) {
            int row = wr * 64 + i * 16 + kg * 4 + r;
            if (row < nRows) {
                size_t crow = (size_t)(cBase + row) * NDM + nBase;
#pragma unroll
                for (int j = 0; j < 4; ++j)
                    projC[crow + wc * 64 + j * 16 + fr] = f2bf(acc[i][j][r]);
            }
        }
    }
}

// ---- kernel 3: ALL output rows; 2 rows/block, 8 floats/thread ----
__global__ void k_out(const int* __restrict__ pos, const int* __restrict__ sid,
                      const int* __restrict__ mod, const int* __restrict__ role,
                      const int* __restrict__ mask, const int* __restrict__ kidx,
                      const int* __restrict__ cnt,
                      const float* __restrict__ bp, const float* __restrict__ cls_c,
                      const float* __restrict__ pe, const float* __restrict__ ie,
                      const float* __restrict__ mrT,
                      const unsigned short* __restrict__ projC,
                      float* __restrict__ out) {
    __shared__ int soff[NS];            // exclusive prefix of cnt (compact offsets)
    if (threadIdx.x == 0) {
        int acc = 0;
        for (int q = 0; q < NS; ++q) { soff[q] = acc; acc += min(cnt[q], EXP_CAP); }
    }
    __syncthreads();
    int rp = threadIdx.x >> 7;          // row of pair
    int o  = (threadIdx.x & 127) * 8;   // 128 threads x 8 floats = 1024
    int l1 = blockIdx.x * 2 + rp;       // 0..2049
    int b  = blockIdx.y;
    if (l1 > NL) return;
    float4 v0, v1;
    if (l1 == 0) {
        const float* ieC = ie + (size_t)NS * NDM;
        v0 = add4(add4(ld4(cls_c + o), ld4(pe + o)), ld4(ieC + o));
        v1 = add4(add4(ld4(cls_c + o + 4), ld4(pe + o + 4)), ld4(ieC + o + 4));
    } else {
        int t = b * NL + l1 - 1;
        int p = pos[t], s = sid[t], mr = mod[t] * 3 + role[t];
        const float* peR = pe + (size_t)p * NDM + o;
        const float* ieR = ie + (size_t)s * NDM + o;
        const float* mrR = mrT + (size_t)mr * NDM + o;
        v0 = add4(add4(ld4(peR), ld4(ieR)), ld4(mrR));
        v1 = add4(add4(ld4(peR + 4), ld4(ieR + 4)), ld4(mrR + 4));
        if (mask[t] != 0) {
            const float* bpR = bp + (size_t)s * NDM + o;
            v0 = add4(v0, ld4(bpR));
            v1 = add4(v1, ld4(bpR + 4));
            int ki = kidx[t];
            if (ki >= 0 && ki < EXP_CAP) {
                const unsigned short* pr = projC + (size_t)(soff[s] + ki) * NDM + o;
                v0.x += bf2f(pr[0]); v0.y += bf2f(pr[1]);
                v0.z += bf2f(pr[2]); v0.w += bf2f(pr[3]);
                v1.x += bf2f(pr[4]); v1.y += bf2f(pr[5]);
                v1.z += bf2f(pr[6]); v1.w += bf2f(pr[7]);
            }
        }
    }
    float* dst = &out[((size_t)b * LP1 + l1) * NDM + o];
    *(float4*)dst = v0;
    *(float4*)(dst + 4) = v1;
}

extern "C" void kernel_launch(void* const* d_in, const int* in_sizes, int n_in,
                              void* d_out, int out_size, void* d_ws, size_t ws_size,
                              hipStream_t stream) {
    const float* emb  = (const float*)d_in[0];
    const int* pos    = (const int*)d_in[1];
    const int* sid    = (const int*)d_in[2];
    const int* mod    = (const int*)d_in[3];
    const int* role   = (const int*)d_in[4];
    const int* mask   = (const int*)d_in[5];   // np.bool_ pushed as int32
    const float* Wp   = (const float*)d_in[6];
    const float* bp   = (const float*)d_in[7];
    const float* cls  = (const float*)d_in[8];
    const float* pe   = (const float*)d_in[9];
    const float* ie   = (const float*)d_in[10];
    const float* me   = (const float*)d_in[11];
    const float* re   = (const float*)d_in[12];
    float* out = (float*)d_out;

    int* ws        = (int*)d_ws;
    int* cnt       = ws;                          // [0..31]
    int* tokList   = ws + 1024;                   // 32*1024
    int* kidx      = ws + 33792;                  // 16384
    float* mrT     = (float*)(ws + 50176);        // 12*1024
    unsigned short* projC = (unsigned short*)((char*)d_ws + 262144);  // 33.55 MB
    // total ws: ~33.8 MB

    hipMemsetAsync(cnt, 0, 32 * sizeof(int), stream);
    k_bucket<<<NTOK / 256, 256, 0, stream>>>(sid, mask, mod, role, me, re,
                                             cnt, kidx, tokList, mrT, out);

    dim3 gg(NDM / 128, MAXTILES);   // N-slice fast -> A-tile L3 reuse
    k_gemm<<<gg, 256, 0, stream>>>(emb, Wp, tokList, cnt, projC);

    dim3 go((LP1 + 1) / 2, NB);
    k_out<<<go, 256, 0, stream>>>(pos, sid, mod, role, mask, kidx, cnt,
                                  bp, cls, pe, ie, mrT, projC, out);
}